// Round 5
// baseline (1599.354 us; speedup 1.0000x reference)
//
#include <hip/hip_runtime.h>
#include <hip/hip_bf16.h>
#include <math.h>

typedef __attribute__((ext_vector_type(8))) short short8;
typedef __attribute__((ext_vector_type(4))) short short4v;
typedef __attribute__((ext_vector_type(4))) float f32x4;
typedef __attribute__((ext_vector_type(4))) int int4v;

#define NH 12
#define DIM 384
#define HD 32

__device__ inline f32x4 mfma16(short8 a, short8 b, f32x4 c){
  return __builtin_amdgcn_mfma_f32_16x16x32_bf16(a, b, c, 0, 0, 0);
}

__device__ inline short fbits(float f){
  __hip_bfloat16 h = __float2bfloat16(f);
  short s; __builtin_memcpy(&s, &h, 2); return s;
}

__device__ inline float wsum16(float v){
  #pragma unroll
  for (int off = 1; off < 16; off <<= 1) v += __shfl_xor(v, off);
  return v;
}
__device__ inline float wmax16(float v){
  #pragma unroll
  for (int off = 1; off < 16; off <<= 1) v = fmaxf(v, __shfl_xor(v, off));
  return v;
}

__device__ inline void gload16(const void* g, void* l){
  __builtin_amdgcn_global_load_lds(
      (const __attribute__((address_space(1))) unsigned int*)g,
      (__attribute__((address_space(3))) unsigned int*)l, 16, 0, 0);
}

__global__ void k_f32_to_bf16(const float* __restrict__ src,
                              __hip_bfloat16* __restrict__ dst, int n){
  int i = blockIdx.x * blockDim.x + threadIdx.x;
  int stride = gridDim.x * blockDim.x;
  for (; i < n; i += stride) dst[i] = __float2bfloat16(src[i]);
}

__device__ inline float cpbf(int a){
  float v = (float)a * (8.0f / 7.0f);
  float s = (v > 0.f) ? 1.f : ((v < 0.f) ? -1.f : 0.f);
  return s * log2f(fabsf(v) + 1.0f) * (1.0f / 3.0f);
}

__global__ __launch_bounds__(256) void k_cpb(
    const float* __restrict__ w1, const float* __restrict__ b1,
    const float* __restrict__ w2, float* __restrict__ hbias)
{
  __shared__ float hid[512];
  int t = blockIdx.x;  // 0..224
  float t0 = cpbf(t / 15 - 7), t1 = cpbf(t % 15 - 7);
  for (int j = threadIdx.x; j < 512; j += 256)
    hid[j] = fmaxf(w1[j * 2 + 0] * t0 + w1[j * 2 + 1] * t1 + b1[j], 0.f);
  __syncthreads();
  if (threadIdx.x < NH){
    float s = 0.f;
    for (int j = 0; j < 512; j++) s += hid[j] * w2[threadIdx.x * 512 + j];
    hbias[t * NH + threadIdx.x] = s;
  }
}

__global__ void k_bias16(const float* __restrict__ hbias,
                         const float* __restrict__ logit_scale,
                         float* __restrict__ bias16, float* __restrict__ scalev)
{
  int i = blockIdx.x * blockDim.x + threadIdx.x;
  if (i < NH) scalev[i] = expf(fminf(logit_scale[i], logf(100.0f)));
  if (i >= NH * 64 * 64) return;
  int h = i >> 12, r = (i >> 6) & 63, c = i & 63;
  int t = ((r >> 3) - (c >> 3) + 7) * 15 + ((r & 7) - (c & 7) + 7);
  float b = hbias[t * NH + h];
  bias16[i] = 16.0f / (1.0f + expf(-b));
}

// ---- xprep: f32 natural order -> bf16 shifted+windowed row order ---------
__global__ __launch_bounds__(256) void k_xprep(
    const float* __restrict__ x, __hip_bfloat16* __restrict__ xb,
    int wr0, int nrow)
{
  int i = blockIdx.x * 256 + threadIdx.x;
  int tot = nrow * 96;
  int stride = gridDim.x * 256;
  for (; i < tot; i += stride){
    int lr = i / 96, j = i - lr * 96;
    int wr = wr0 + lr;
    int wi = wr >> 6, t = wr & 63;
    int bb = wi >> 6, wh = (wi >> 3) & 7, ww = wi & 7;
    int h = (wh * 8 + (t >> 3) + 4) & 63;
    int w2 = (ww * 8 + (t & 7) + 4) & 63;
    float4 f = ((const float4*)(x + ((size_t)(bb << 12) + (h << 6) + w2) * DIM))[j];
    short4v o;
    o[0] = fbits(f.x); o[1] = fbits(f.y); o[2] = fbits(f.z); o[3] = fbits(f.w);
    *(short4v*)(xb + (size_t)lr * DIM + j * 4) = o;
  }
}

// ---- qkv GEMM: [Mc][384] @ [1152][384]^T, fused bias/norm/scale/v-transp --
__global__ __launch_bounds__(256, 3) void k_qkv(
    const __hip_bfloat16* __restrict__ xb,     // [Mc][384] chunk-local
    const __hip_bfloat16* __restrict__ w,      // [1152][384]
    const float* __restrict__ bias,            // [1152]
    const float* __restrict__ scalev,          // [12]
    __hip_bfloat16* __restrict__ qb,           // [Mc][384]
    __hip_bfloat16* __restrict__ kb,           // [Mc][384]
    __hip_bfloat16* __restrict__ vT)           // [Mc/64][12][32][64]
{
  __shared__ __attribute__((aligned(16))) char stage[2][16384];
  const int tid = threadIdx.x, lane = tid & 63, wid = tid >> 6;
  const int colb = lane & 15, hi = lane >> 4;
  const int mt = blockIdx.x / 9, nt = blockIdx.x % 9;
  const size_t row0 = (size_t)mt * 128;
  const int col0 = nt * 128;
  const int wm = wid >> 1, wn = wid & 1;

  auto stg = [&](int buf, int kc){
    #pragma unroll
    for (int j = 0; j < 4; j++){
      int s = wid * 4 + j;
      const __hip_bfloat16* src;
      if (s < 8) src = xb + (row0 + s * 16 + colb) * DIM + kc * 32 + hi * 8;
      else       src = w + (size_t)(col0 + (s - 8) * 16 + colb) * DIM + kc * 32 + hi * 8;
      gload16(src, &stage[buf][s * 1024]);
    }
  };

  f32x4 acc[4][4];
  #pragma unroll
  for (int mi = 0; mi < 4; mi++)
    #pragma unroll
    for (int ni = 0; ni < 4; ni++) acc[mi][ni] = (f32x4)(0.f);

  int buf = 0;
  stg(0, 0);
  __syncthreads();
  for (int kc = 0; kc < 12; kc++){
    if (kc < 11) stg(buf ^ 1, kc + 1);
    short8 a[4], b[4];
    #pragma unroll
    for (int mi = 0; mi < 4; mi++)
      a[mi] = *(const short8*)&stage[buf][(wm * 4 + mi) * 1024 + lane * 16];
    #pragma unroll
    for (int ni = 0; ni < 4; ni++)
      b[ni] = *(const short8*)&stage[buf][(8 + wn * 4 + ni) * 1024 + lane * 16];
    #pragma unroll
    for (int mi = 0; mi < 4; mi++)
      #pragma unroll
      for (int ni = 0; ni < 4; ni++)
        acc[mi][ni] = mfma16(a[mi], b[ni], acc[mi][ni]);
    __syncthreads();
    buf ^= 1;
  }

  const int seg = nt / 3;                       // 0=q 1=k 2=v
  const int segc0 = (nt % 3) * 128 + wn * 64;   // wave's first col in segment

  if (seg < 2){
    // +bias
    #pragma unroll
    for (int ni = 0; ni < 4; ni++){
      float fb = bias[seg * DIM + segc0 + ni * 16 + colb];
      #pragma unroll
      for (int mi = 0; mi < 4; mi++)
        #pragma unroll
        for (int rr = 0; rr < 4; rr++) acc[mi][ni][rr] += fb;
    }
    // per-head (32-dim) cosine norm; fold logit scale into q
    #pragma unroll
    for (int mi = 0; mi < 4; mi++)
      #pragma unroll
      for (int rr = 0; rr < 4; rr++)
        #pragma unroll
        for (int hh = 0; hh < 2; hh++){
          float s = acc[mi][2*hh][rr] * acc[mi][2*hh][rr]
                  + acc[mi][2*hh+1][rr] * acc[mi][2*hh+1][rr];
          s = wsum16(s);
          float inv = 1.0f / fmaxf(sqrtf(s), 1e-12f);
          if (seg == 0) inv *= scalev[(segc0 >> 5) + hh];
          acc[mi][2*hh][rr] *= inv;
          acc[mi][2*hh+1][rr] *= inv;
        }
    __hip_bfloat16* dst = (seg == 0) ? qb : kb;
    #pragma unroll
    for (int mi = 0; mi < 4; mi++)
      #pragma unroll
      for (int ni = 0; ni < 4; ni++)
        #pragma unroll
        for (int rr = 0; rr < 4; rr++)
          dst[(row0 + wm * 64 + mi * 16 + hi * 4 + rr) * DIM
              + segc0 + ni * 16 + colb] = __float2bfloat16(acc[mi][ni][rr]);
  } else {
    // v: +bias, write transposed per window: vT[lwi][head][dim][token]
    const int lwi = mt * 2 + wm;
    #pragma unroll
    for (int ni = 0; ni < 4; ni++){
      float fb = bias[2 * DIM + segc0 + ni * 16 + colb];
      int head = (segc0 >> 5) + (ni >> 1);
      int d = (ni & 1) * 16 + colb;
      #pragma unroll
      for (int mi = 0; mi < 4; mi++){
        short4v pk;
        #pragma unroll
        for (int rr = 0; rr < 4; rr++) pk[rr] = fbits(acc[mi][ni][rr] + fb);
        *(short4v*)(vT + ((size_t)(lwi * NH + head) * 32 + d) * 64
                       + mi * 16 + hi * 4) = pk;
      }
    }
  }
}

// ---- per-window attention: QK^T + bias/mask + softmax + PV ---------------
__global__ __launch_bounds__(256, 3) void k_win(
    const __hip_bfloat16* __restrict__ qb,     // [Mc][384] chunk-local
    const __hip_bfloat16* __restrict__ kb,
    const __hip_bfloat16* __restrict__ vT,     // [Mc/64][12][32][64]
    const float* __restrict__ bias16,          // [12][64][64]
    __hip_bfloat16* __restrict__ attnout,      // global, windowed rows
    int wi0)
{
  __shared__ short Plds[4][64][72];
  __shared__ int lbl[64];
  const int tid = threadIdx.x, lane = tid & 63, wid = tid >> 6;
  const int colb = lane & 15, hi = lane >> 4;
  const int lwi = blockIdx.x;
  const int wi = wi0 + lwi;

  if (tid < 64){
    int wh = (wi >> 3) & 7, ww = wi & 7;
    int hp = wh * 8 + (tid >> 3), wp = ww * 8 + (tid & 7);
    int rh = (hp < 56) ? 0 : (hp < 60 ? 1 : 2);
    int rw = (wp < 56) ? 0 : (wp < 60 ? 1 : 2);
    lbl[tid] = rh * 3 + rw;
  }
  __syncthreads();

  int lblc[4], lblr[4][4];
  #pragma unroll
  for (int ni = 0; ni < 4; ni++) lblc[ni] = lbl[ni * 16 + colb];
  #pragma unroll
  for (int mi = 0; mi < 4; mi++)
    #pragma unroll
    for (int rr = 0; rr < 4; rr++) lblr[mi][rr] = lbl[mi * 16 + hi * 4 + rr];

  for (int h3 = 0; h3 < 3; h3++){
    const int head = wid * 3 + h3;
    // QK^T (scale already folded into q)
    short8 qf[4], kf[4];
    #pragma unroll
    for (int mi = 0; mi < 4; mi++)
      qf[mi] = *(const short8*)(qb + ((size_t)lwi * 64 + mi * 16 + colb) * DIM
                                   + head * HD + hi * 8);
    #pragma unroll
    for (int ni = 0; ni < 4; ni++)
      kf[ni] = *(const short8*)(kb + ((size_t)lwi * 64 + ni * 16 + colb) * DIM
                                   + head * HD + hi * 8);
    f32x4 s[4][4];
    #pragma unroll
    for (int mi = 0; mi < 4; mi++)
      #pragma unroll
      for (int ni = 0; ni < 4; ni++) s[mi][ni] = (f32x4)(0.f);
    #pragma unroll
    for (int ni = 0; ni < 4; ni++)
      #pragma unroll
      for (int mi = 0; mi < 4; mi++)
        s[mi][ni] = mfma16(qf[mi], kf[ni], s[mi][ni]);

    // bias + mask + wave-parallel softmax, P -> per-wave LDS tile
    const float* bp = bias16 + (size_t)head * 4096;
    #pragma unroll
    for (int mi = 0; mi < 4; mi++)
      #pragma unroll
      for (int rr = 0; rr < 4; rr++){
        int row = mi * 16 + hi * 4 + rr;
        int li = lblr[mi][rr];
        float e[4]; float mx = -3e38f;
        #pragma unroll
        for (int ni = 0; ni < 4; ni++){
          float t = s[mi][ni][rr] + bp[row * 64 + ni * 16 + colb]
                    + ((lblc[ni] == li) ? 0.f : -100.f);
          e[ni] = t; mx = fmaxf(mx, t);
        }
        mx = wmax16(mx);
        float sm = 0.f;
        #pragma unroll
        for (int ni = 0; ni < 4; ni++){ e[ni] = __expf(e[ni] - mx); sm += e[ni]; }
        sm = wsum16(sm);
        float is = 1.0f / sm;
        #pragma unroll
        for (int ni = 0; ni < 4; ni++)
          Plds[wid][row][ni * 16 + colb] = fbits(e[ni] * is);
      }

    // PV
    f32x4 o[4][2];
    #pragma unroll
    for (int mi = 0; mi < 4; mi++){ o[mi][0] = (f32x4)(0.f); o[mi][1] = (f32x4)(0.f); }
    #pragma unroll
    for (int kc = 0; kc < 2; kc++){
      short8 pf[4], vf[2];
      #pragma unroll
      for (int mi = 0; mi < 4; mi++)
        pf[mi] = *(const short8*)&Plds[wid][mi * 16 + colb][kc * 32 + hi * 8];
      #pragma unroll
      for (int ni = 0; ni < 2; ni++)
        vf[ni] = *(const short8*)(vT + ((size_t)(lwi * NH + head) * 32
                                        + ni * 16 + colb) * 64 + kc * 32 + hi * 8);
      #pragma unroll
      for (int mi = 0; mi < 4; mi++)
        #pragma unroll
        for (int ni = 0; ni < 2; ni++)
          o[mi][ni] = mfma16(pf[mi], vf[ni], o[mi][ni]);
    }
    #pragma unroll
    for (int mi = 0; mi < 4; mi++)
      #pragma unroll
      for (int ni = 0; ni < 2; ni++)
        #pragma unroll
        for (int rr = 0; rr < 4; rr++)
          attnout[((size_t)wi * 64 + mi * 16 + hi * 4 + rr) * DIM
                  + head * HD + ni * 16 + colb] = __float2bfloat16(o[mi][ni][rr]);
  }
}

// ---- proj: M=64 x N=384(full) x K=384 GEMM + LN1 + unshift + residual ----
__global__ __launch_bounds__(256, 2) void k_proj(
    const __hip_bfloat16* __restrict__ attnout,
    const __hip_bfloat16* __restrict__ projw,
    const float* __restrict__ projb,
    const float* __restrict__ x,
    const float* __restrict__ g1, const float* __restrict__ b1v,
    __hip_bfloat16* __restrict__ yout)
{
  __shared__ __attribute__((aligned(16))) char stage[2][28672];  // 28 slots
  __shared__ float red1[64][4], red2[64][4];
  const int tid = threadIdx.x, lane = tid & 63, wid = tid >> 6;
  const int colb = lane & 15, hi = lane >> 4;
  const size_t row0 = (size_t)blockIdx.x * 64;

  auto stg = [&](int buf, int kc){
    #pragma unroll
    for (int j = 0; j < 7; j++){
      int s = wid * 7 + j;
      const __hip_bfloat16* src;
      if (s < 4) src = attnout + (row0 + s * 16 + colb) * DIM + kc * 32 + hi * 8;
      else       src = projw + (size_t)((s - 4) * 16 + colb) * DIM + kc * 32 + hi * 8;
      gload16(src, &stage[buf][s * 1024]);
    }
  };

  f32x4 acc[4][6];
  #pragma unroll
  for (int mi = 0; mi < 4; mi++)
    #pragma unroll
    for (int ni = 0; ni < 6; ni++) acc[mi][ni] = (f32x4)(0.f);

  int buf = 0;
  stg(0, 0);
  __syncthreads();
  for (int kc = 0; kc < 12; kc++){
    if (kc < 11) stg(buf ^ 1, kc + 1);
    short8 a[4], b[6];
    #pragma unroll
    for (int mi = 0; mi < 4; mi++)
      a[mi] = *(const short8*)&stage[buf][mi * 1024 + lane * 16];
    #pragma unroll
    for (int ni = 0; ni < 6; ni++)
      b[ni] = *(const short8*)&stage[buf][(4 + wid * 6 + ni) * 1024 + lane * 16];
    #pragma unroll
    for (int mi = 0; mi < 4; mi++)
      #pragma unroll
      for (int ni = 0; ni < 6; ni++)
        acc[mi][ni] = mfma16(a[mi], b[ni], acc[mi][ni]);
    __syncthreads();
    buf ^= 1;
  }

  float s1[4][4], s2[4][4];
  #pragma unroll
  for (int mi = 0; mi < 4; mi++)
    #pragma unroll
    for (int rr = 0; rr < 4; rr++){ s1[mi][rr] = 0.f; s2[mi][rr] = 0.f; }
  #pragma unroll
  for (int ni = 0; ni < 6; ni++){
    float pb = projb[wid * 96 + ni * 16 + colb];
    #pragma unroll
    for (int mi = 0; mi < 4; mi++)
      #pragma unroll
      for (int rr = 0; rr < 4; rr++){
        float v = acc[mi][ni][rr] + pb;
        acc[mi][ni][rr] = v;
        s1[mi][rr] += v; s2[mi][rr] += v * v;
      }
  }
  #pragma unroll
  for (int mi = 0; mi < 4; mi++)
    #pragma unroll
    for (int rr = 0; rr < 4; rr++){
      float a = wsum16(s1[mi][rr]);
      float b = wsum16(s2[mi][rr]);
      if (colb == 0){
        int row = mi * 16 + hi * 4 + rr;
        red1[row][wid] = a; red2[row][wid] = b;
      }
    }
  __syncthreads();

  #pragma unroll
  for (int mi = 0; mi < 4; mi++)
    #pragma unroll
    for (int rr = 0; rr < 4; rr++){
      int row = mi * 16 + hi * 4 + rr;
      float t1 = red1[row][0] + red1[row][1] + red1[row][2] + red1[row][3];
      float t2 = red2[row][0] + red2[row][1] + red2[row][2] + red2[row][3];
      float mean = t1 * (1.f / 384.f);
      float var  = t2 * (1.f / 384.f) - mean * mean;
      float inv  = rsqrtf(var + 1e-5f);
      size_t arow = row0 + row;
      int wi2 = (int)(arow >> 6), t = (int)(arow & 63);
      int bb = wi2 >> 6, wh = (wi2 >> 3) & 7, ww = wi2 & 7;
      int rr2 = t >> 3, cc = t & 7;
      int h = (wh * 8 + rr2 + 4) & 63, w = (ww * 8 + cc + 4) & 63;
      size_t gpos = ((size_t)bb << 12) + (h << 6) + w;
      const float* xp = x + gpos * DIM;
      __hip_bfloat16* yp = yout + gpos * DIM;
      #pragma unroll
      for (int ni = 0; ni < 6; ni++){
        int c = wid * 96 + ni * 16 + colb;
        float ln = (acc[mi][ni][rr] - mean) * inv * g1[c] + b1v[c];
        yp[c] = __float2bfloat16(xp[c] + ln);
      }
    }
}

// ---- fc1: 128x128 tile GEMM (K=384) + bias + GELU -> h bf16 --------------
__global__ __launch_bounds__(256, 3) void k_fc1(
    const __hip_bfloat16* __restrict__ y,      // [Mchunk][384]
    const __hip_bfloat16* __restrict__ fc1w,   // [1536][384]
    const float* __restrict__ fc1b,
    __hip_bfloat16* __restrict__ h)            // [Mchunk][1536]
{
  __shared__ __attribute__((aligned(16))) char stage[2][16384];  // 16 slots
  const int tid = threadIdx.x, lane = tid & 63, wid = tid >> 6;
  const int colb = lane & 15, hi = lane >> 4;
  const int mt = blockIdx.x / 12, nt = blockIdx.x % 12;
  const size_t row0 = (size_t)mt * 128;
  const int col0 = nt * 128;
  const int wm = wid >> 1, wn = wid & 1;

  auto stg = [&](int buf, int kc){
    #pragma unroll
    for (int j = 0; j < 4; j++){
      int s = wid * 4 + j;
      const __hip_bfloat16* src;
      if (s < 8) src = y + (row0 + s * 16 + colb) * DIM + kc * 32 + hi * 8;
      else       src = fc1w + (size_t)(col0 + (s - 8) * 16 + colb) * DIM + kc * 32 + hi * 8;
      gload16(src, &stage[buf][s * 1024]);
    }
  };

  f32x4 acc[4][4];
  #pragma unroll
  for (int mi = 0; mi < 4; mi++)
    #pragma unroll
    for (int ni = 0; ni < 4; ni++) acc[mi][ni] = (f32x4)(0.f);

  int buf = 0;
  stg(0, 0);
  __syncthreads();
  for (int kc = 0; kc < 12; kc++){
    if (kc < 11) stg(buf ^ 1, kc + 1);
    short8 a[4], b[4];
    #pragma unroll
    for (int mi = 0; mi < 4; mi++)
      a[mi] = *(const short8*)&stage[buf][(wm * 4 + mi) * 1024 + lane * 16];
    #pragma unroll
    for (int ni = 0; ni < 4; ni++)
      b[ni] = *(const short8*)&stage[buf][(8 + wn * 4 + ni) * 1024 + lane * 16];
    #pragma unroll
    for (int mi = 0; mi < 4; mi++)
      #pragma unroll
      for (int ni = 0; ni < 4; ni++)
        acc[mi][ni] = mfma16(a[mi], b[ni], acc[mi][ni]);
    __syncthreads();
    buf ^= 1;
  }

  #pragma unroll
  for (int ni = 0; ni < 4; ni++){
    int c = col0 + wn * 64 + ni * 16 + colb;
    float fb = fc1b[c];
    #pragma unroll
    for (int mi = 0; mi < 4; mi++){
      size_t rbase = row0 + wm * 64 + mi * 16 + hi * 4;
      #pragma unroll
      for (int rr = 0; rr < 4; rr++){
        float v = acc[mi][ni][rr] + fb;
        float u = v * (1.0f + 0.044715f * v * v);
        float gl = v / (1.0f + __expf(-1.5957691216f * u));
        h[(rbase + rr) * 1536 + c] = __float2bfloat16(gl);
      }
    }
  }
}

// ---- fc2: M=64 x N=384(full) x K=1536 GEMM + LN2 + residual -> out f32 ---
__global__ __launch_bounds__(256, 2) void k_fc2(
    const __hip_bfloat16* __restrict__ h,      // [Mchunk][1536]
    const __hip_bfloat16* __restrict__ fc2w,   // [384][1536]
    const float* __restrict__ fc2b,
    const __hip_bfloat16* __restrict__ y,      // residual
    const float* __restrict__ g2, const float* __restrict__ b2v,
    float* __restrict__ out)
{
  __shared__ __attribute__((aligned(16))) char stage[2][28672];  // 28 slots
  __shared__ float red1[64][4], red2[64][4];
  const int tid = threadIdx.x, lane = tid & 63, wid = tid >> 6;
  const int colb = lane & 15, hi = lane >> 4;
  const size_t row0 = (size_t)blockIdx.x * 64;

  auto stg = [&](int buf, int kc){
    #pragma unroll
    for (int j = 0; j < 7; j++){
      int s = wid * 7 + j;
      const __hip_bfloat16* src;
      if (s < 4) src = h + (row0 + s * 16 + colb) * 1536 + kc * 32 + hi * 8;
      else       src = fc2w + (size_t)((s - 4) * 16 + colb) * 1536 + kc * 32 + hi * 8;
      gload16(src, &stage[buf][s * 1024]);
    }
  };

  f32x4 acc[4][6];
  #pragma unroll
  for (int mi = 0; mi < 4; mi++)
    #pragma unroll
    for (int ni = 0; ni < 6; ni++) acc[mi][ni] = (f32x4)(0.f);

  int buf = 0;
  stg(0, 0);
  __syncthreads();
  for (int kc = 0; kc < 48; kc++){
    if (kc < 47) stg(buf ^ 1, kc + 1);
    short8 a[4], b[6];
    #pragma unroll
    for (int mi = 0; mi < 4; mi++)
      a[mi] = *(const short8*)&stage[buf][mi * 1024 + lane * 16];
    #pragma unroll
    for (int ni = 0; ni < 6; ni++)
      b[ni] = *(const short8*)&stage[buf][(4 + wid * 6 + ni) * 1024 + lane * 16];
    #pragma unroll
    for (int mi = 0; mi < 4; mi++)
      #pragma unroll
      for (int ni = 0; ni < 6; ni++)
        acc[mi][ni] = mfma16(a[mi], b[ni], acc[mi][ni]);
    __syncthreads();
    buf ^= 1;
  }

  float s1[4][4], s2[4][4];
  #pragma unroll
  for (int mi = 0; mi < 4; mi++)
    #pragma unroll
    for (int rr = 0; rr < 4; rr++){ s1[mi][rr] = 0.f; s2[mi][rr] = 0.f; }
  #pragma unroll
  for (int ni = 0; ni < 6; ni++){
    float fb = fc2b[wid * 96 + ni * 16 + colb];
    #pragma unroll
    for (int mi = 0; mi < 4; mi++)
      #pragma unroll
      for (int rr = 0; rr < 4; rr++){
        float v = acc[mi][ni][rr] + fb;
        acc[mi][ni][rr] = v;
        s1[mi][rr] += v; s2[mi][rr] += v * v;
      }
  }
  #pragma unroll
  for (int mi = 0; mi < 4; mi++)
    #pragma unroll
    for (int rr = 0; rr < 4; rr++){
      float a = wsum16(s1[mi][rr]);
      float b = wsum16(s2[mi][rr]);
      if (colb == 0){
        int row = mi * 16 + hi * 4 + rr;
        red1[row][wid] = a; red2[row][wid] = b;
      }
    }
  __syncthreads();

  #pragma unroll
  for (int mi = 0; mi < 4; mi++)
    #pragma unroll
    for (int rr = 0; rr < 4; rr++){
      int row = mi * 16 + hi * 4 + rr;
      float t1 = red1[row][0] + red1[row][1] + red1[row][2] + red1[row][3];
      float t2 = red2[row][0] + red2[row][1] + red2[row][2] + red2[row][3];
      float mean = t1 * (1.f / 384.f);
      float var  = t2 * (1.f / 384.f) - mean * mean;
      float inv  = rsqrtf(var + 1e-5f);
      size_t grow = row0 + row;
      const __hip_bfloat16* yp = y + grow * DIM;
      float* op = out + grow * DIM;
      #pragma unroll
      for (int ni = 0; ni < 6; ni++){
        int c = wid * 96 + ni * 16 + colb;
        float ln = (acc[mi][ni][rr] - mean) * inv * g2[c] + b2v[c];
        op[c] = __bfloat162float(yp[c]) + ln;
      }
    }
}

extern "C" void kernel_launch(void* const* d_in, const int* in_sizes, int n_in,
                              void* d_out, int out_size, void* d_ws, size_t ws_size,
                              hipStream_t stream)
{
  (void)in_sizes; (void)n_in; (void)out_size;
  const float* x    = (const float*)d_in[0];
  const float* qkvw_f = (const float*)d_in[3];
  const float* qkvb = (const float*)d_in[4];
  const float* lsc  = (const float*)d_in[5];
  const float* cw1  = (const float*)d_in[6];
  const float* cb1  = (const float*)d_in[7];
  const float* cw2  = (const float*)d_in[8];
  const float* pw   = (const float*)d_in[9];
  const float* pb   = (const float*)d_in[10];
  const float* g1   = (const float*)d_in[11];
  const float* b1   = (const float*)d_in[12];
  const float* g2   = (const float*)d_in[13];
  const float* b2   = (const float*)d_in[14];
  const float* f1w  = (const float*)d_in[15];
  const float* f1b  = (const float*)d_in[16];
  const float* f2w  = (const float*)d_in[17];
  const float* f2b  = (const float*)d_in[18];

  char* ws = (char*)d_ws;
  size_t off = 0;
  auto alloc = [&](size_t bytes) -> char* {
    char* p = ws + off;
    off += (bytes + 255) & ~(size_t)255;
    return p;
  };
  __hip_bfloat16* qkvw_h  = (__hip_bfloat16*)alloc((size_t)1152 * 384 * 2);
  __hip_bfloat16* projw_h = (__hip_bfloat16*)alloc((size_t)384 * 384 * 2);
  __hip_bfloat16* fc1w_h  = (__hip_bfloat16*)alloc((size_t)1536 * 384 * 2);
  __hip_bfloat16* fc2w_h  = (__hip_bfloat16*)alloc((size_t)384 * 1536 * 2);
  float* scalev = (float*)alloc(NH * 4);
  float* hbias  = (float*)alloc(225 * NH * 4);
  float* bias16 = (float*)alloc((size_t)NH * 64 * 64 * 4);
  __hip_bfloat16* attnout = (__hip_bfloat16*)alloc((size_t)131072 * DIM * 2);
  __hip_bfloat16* yb      = (__hip_bfloat16*)alloc((size_t)131072 * DIM * 2);
  size_t base = off;

  // adaptive chunking of the attention intermediates (xb,q,k,vT: 4x Mc*768 B)
  int nch = 32;
  const int opts[6] = {1, 2, 4, 8, 16, 32};
  for (int ii = 0; ii < 6; ii++){
    size_t mc = (size_t)131072 / opts[ii];
    if (base + 4 * mc * 768 + 4096 <= ws_size){ nch = opts[ii]; break; }
  }
  size_t Mc = (size_t)131072 / nch;
  __hip_bfloat16* xbc = (__hip_bfloat16*)alloc(Mc * 768);
  __hip_bfloat16* qc  = (__hip_bfloat16*)alloc(Mc * 768);
  __hip_bfloat16* kc  = (__hip_bfloat16*)alloc(Mc * 768);
  __hip_bfloat16* vTc = (__hip_bfloat16*)alloc(Mc * 768);
  __hip_bfloat16* hbuf = attnout;   // h overlays attnout (dead after k_proj)

  k_f32_to_bf16<<<512, 256, 0, stream>>>(qkvw_f, qkvw_h, 1152 * 384);
  k_f32_to_bf16<<<256, 256, 0, stream>>>(pw, projw_h, 384 * 384);
  k_f32_to_bf16<<<512, 256, 0, stream>>>(f1w, fc1w_h, 1536 * 384);
  k_f32_to_bf16<<<512, 256, 0, stream>>>(f2w, fc2w_h, 384 * 1536);
  k_cpb<<<225, 256, 0, stream>>>(cw1, cb1, cw2, hbias);
  k_bias16<<<192, 256, 0, stream>>>(hbias, lsc, bias16, scalev);

  for (int c = 0; c < nch; c++){
    int wr0 = (int)(c * Mc);
    k_xprep<<<1024, 256, 0, stream>>>(x, xbc, wr0, (int)Mc);
    k_qkv<<<(int)(Mc / 128) * 9, 256, 0, stream>>>(xbc, qkvw_h, qkvb, scalev,
                                                   qc, kc, vTc);
    k_win<<<(int)(Mc / 64), 256, 0, stream>>>(qc, kc, vTc, bias16, attnout,
                                              wr0 / 64);
  }

  k_proj<<<2048, 256, 0, stream>>>(attnout, projw_h, pb, x, g1, b1, yb);

  for (int c = 0; c < 4; c++){
    size_t ro = (size_t)c * 32768;
    k_fc1<<<3072, 256, 0, stream>>>(yb + ro * DIM, fc1w_h, f1b, hbuf);
    k_fc2<<<512, 256, 0, stream>>>(hbuf, fc2w_h, f2b, yb + ro * DIM,
                                   g2, b2, (float*)d_out + ro * DIM);
  }
}